// Round 9
// baseline (2269.020 us; speedup 1.0000x reference)
//
#include <hip/hip_runtime.h>

#define B_ 2
#define N_ 6
#define D_ 41
#define H_ 16
#define W_ 44
#define C_ 64
#define X_ 200
#define Y_ 200
#define NPTS (B_*N_*D_*H_*W_)   // 346368
#define NBN (B_*N_)             // 12
#define NCELL (B_*X_*Y_)        // 80000
#define MAT_STRIDE 24           // doubles per (b,n)
#define CPB 320                 // cells per bucket
#define NBUCK (NCELL/CPB)       // 250 (exact)
#define BPB 125                 // buckets per batch-image (40000/320)
#define LDSW 65                 // padded LDS row width

__device__ inline void inv3x3(const double m[9], double out[9]) {
    double a=m[0],b=m[1],c=m[2],d=m[3],e=m[4],f=m[5],g=m[6],h=m[7],i=m[8];
    double A  =  (e*i - f*h);
    double Bm = -(d*i - f*g);
    double Cm =  (d*h - e*g);
    double det = a*A + b*Bm + c*Cm;
    double id = 1.0/det;
    out[0] = A*id;   out[1] = -(b*i - c*h)*id; out[2] =  (b*f - c*e)*id;
    out[3] = Bm*id;  out[4] =  (a*i - c*g)*id; out[5] = -(a*f - c*d)*id;
    out[6] = Cm*id;  out[7] = -(a*h - b*g)*id; out[8] =  (a*e - b*d)*id;
}

// One thread per (b,n): inv(post_rots), comb = rot(inv(extr)) @ inv(K), trans.
__global__ void prep_kernel(const float* __restrict__ post_rots,
                            const float* __restrict__ intr,
                            const float* __restrict__ extr,
                            double* __restrict__ mats) {
    int bn = threadIdx.x;
    if (bn >= NBN) return;

    double pr[9], prinv[9], kk[9], kin[9];
    for (int i=0;i<9;i++) pr[i] = (double)post_rots[bn*9+i];
    inv3x3(pr, prinv);
    for (int i=0;i<9;i++) kk[i] = (double)intr[bn*9+i];
    inv3x3(kk, kin);

    const float* E = extr + bn*16;
    double a00=E[0], a01=E[1], a02=E[2], a03=E[3];
    double a10=E[4], a11=E[5], a12=E[6], a13=E[7];
    double a20=E[8], a21=E[9], a22=E[10], a23=E[11];
    double a30=E[12], a31=E[13], a32=E[14], a33=E[15];

    double s0=a00*a11-a10*a01, s1=a00*a12-a10*a02, s2=a00*a13-a10*a03;
    double s3=a01*a12-a11*a02, s4=a01*a13-a11*a03, s5=a02*a13-a12*a03;
    double c5=a22*a33-a32*a23, c4=a21*a33-a31*a23, c3=a21*a32-a31*a22;
    double c2=a20*a33-a30*a23, c1=a20*a32-a30*a22, c0=a20*a31-a30*a21;
    double det = s0*c5 - s1*c4 + s2*c3 + s3*c2 - s4*c1 + s5*c0;
    double iv = 1.0/det;

    double rot[9], trans[3];
    rot[0] = ( a11*c5 - a12*c4 + a13*c3)*iv;
    rot[1] = (-a01*c5 + a02*c4 - a03*c3)*iv;
    rot[2] = ( a31*s5 - a32*s4 + a33*s3)*iv;
    trans[0]=(-a21*s5 + a22*s4 - a23*s3)*iv;
    rot[3] = (-a10*c5 + a12*c2 - a13*c1)*iv;
    rot[4] = ( a00*c5 - a02*c2 + a03*c1)*iv;
    rot[5] = (-a30*s5 + a32*s2 - a33*s1)*iv;
    trans[1]=( a20*s5 - a22*s2 + a23*s1)*iv;
    rot[6] = ( a10*c4 - a11*c2 + a13*c0)*iv;
    rot[7] = (-a00*c4 + a01*c2 - a03*c0)*iv;
    rot[8] = ( a30*s4 - a31*s2 + a33*s0)*iv;
    trans[2]=(-a20*s4 + a21*s2 - a23*s0)*iv;

    double comb[9];
    for (int i=0;i<3;i++) for (int j=0;j<3;j++)
        comb[i*3+j] = rot[i*3+0]*kin[0+j] + rot[i*3+1]*kin[3+j] + rot[i*3+2]*kin[6+j];

    double* o = mats + (size_t)bn*MAT_STRIDE;
    for (int i=0;i<9;i++) o[i]   = prinv[i];
    for (int i=0;i<9;i++) o[9+i] = comb[i];
    for (int i=0;i<3;i++) o[18+i]= trans[i];
}

// One THREAD per point: cell id (or -1), plus LDS bucket histogram.
__global__ __launch_bounds__(256)
void geom_kernel(const float* __restrict__ post_trans,
                 const float* __restrict__ frustum,
                 const float* __restrict__ bev_res,
                 const float* __restrict__ bev_start,
                 const double* __restrict__ mats,
                 int* __restrict__ rank, int* __restrict__ bhist) {
    __shared__ int sh[NBUCK];
    for (int i = threadIdx.x; i < NBUCK; i += 256) sh[i] = 0;
    __syncthreads();

    int p = blockIdx.x * blockDim.x + threadIdx.x;
    if (p < NPTS) {
        int w = p % W_; int t = p / W_;
        int h = t % H_;  t /= H_;
        int d = t % D_;  t /= D_;
        int bn = t;      int b = bn / N_;

        const double* M = mats + (size_t)bn*MAT_STRIDE;
        int fidx = ((d*H_ + h)*W_ + w)*3;
        double fx = (double)frustum[fidx+0];
        double fy = (double)frustum[fidx+1];
        double fz = (double)frustum[fidx+2];

        double px = fx - (double)post_trans[bn*3+0];
        double py = fy - (double)post_trans[bn*3+1];
        double pz = fz - (double)post_trans[bn*3+2];

        double q0 = M[0]*px + M[1]*py + M[2]*pz;
        double q1 = M[3]*px + M[4]*py + M[5]*pz;
        double q2 = M[6]*px + M[7]*py + M[8]*pz;

        double r0 = q0*q2, r1 = q1*q2, r2 = q2;

        double gx = M[9]*r0  + M[10]*r1 + M[11]*r2 + M[18];
        double gy = M[12]*r0 + M[13]*r1 + M[14]*r2 + M[19];
        double gz = M[15]*r0 + M[16]*r1 + M[17]*r2 + M[20];

        double resx = (double)bev_res[0], resy = (double)bev_res[1], resz = (double)bev_res[2];
        double sx = (double)bev_start[0] - resx*0.5;
        double sy = (double)bev_start[1] - resy*0.5;
        double sz = (double)bev_start[2] - resz*0.5;

        int cx = (int)((gx - sx)/resx);
        int cy = (int)((gy - sy)/resy);
        int cz = (int)((gz - sz)/resz);

        int cell = -1;
        if (cx >= 0 && cx < X_ && cy >= 0 && cy < Y_ && cz == 0) {
            cell = (b*X_ + cx)*Y_ + cy;
            atomicAdd(&sh[cell / CPB], 1);
        }
        rank[p] = cell;
    }
    __syncthreads();
    for (int i = threadIdx.x; i < NBUCK; i += 256)
        if (sh[i]) atomicAdd(&bhist[i], sh[i]);
}

// Single-block scan of 250 bucket counts.
__global__ __launch_bounds__(256)
void scanb_kernel(const int* __restrict__ bhist,
                  int* __restrict__ offs, int* __restrict__ cursor) {
    __shared__ int s[256];
    int t = threadIdx.x;
    int v = (t < NBUCK) ? bhist[t] : 0;
    s[t] = v;
    __syncthreads();
    for (int o = 1; o < 256; o <<= 1) {
        int a = (t >= o) ? s[t - o] : 0;
        __syncthreads();
        s[t] += a;
        __syncthreads();
    }
    if (t < NBUCK) { offs[t] = s[t] - v; cursor[t] = s[t] - v; }
    if (t == NBUCK - 1) offs[NBUCK] = s[t];
}

// Bucket-scatter: sequential feat read; writes form 250 quasi-sequential streams
// of full 256B-aligned rows (large effective granularity, write-combinable).
__global__ __launch_bounds__(256)
void fill3_kernel(const float* __restrict__ feat,
                  const int* __restrict__ rank,
                  int* __restrict__ cursor,
                  float* __restrict__ sfeat, int* __restrict__ clist) {
    int tid = blockIdx.x * blockDim.x + threadIdx.x;
    int p = tid >> 6, lane = tid & 63;
    if (p >= NPTS) return;
    int cell = rank[p];
    if (cell < 0) return;
    int pos = 0;
    if (lane == 0) pos = atomicAdd(&cursor[cell / CPB], 1);
    pos = __shfl(pos, 0);
    sfeat[(size_t)pos*C_ + lane] = feat[(size_t)p*C_ + lane];
    if (lane == 0) clist[pos] = cell;
}

// Exclusive-ownership accumulate: block = bucket (320 cells), LDS f32 accumulate,
// direct coalesced (B,C,X,Y) output write. Zero global atomics. Covers ALL cells.
__global__ __launch_bounds__(256)
void accum_kernel(const float* __restrict__ sfeat,
                  const int* __restrict__ clist,
                  const int* __restrict__ offs,
                  float* __restrict__ out) {
    __shared__ float acc[CPB * LDSW];   // 83.2 KB, padded: conflict-free both phases
    int buck = blockIdx.x;
    int tid = threadIdx.x, lane = tid & 63, wid = tid >> 6;

    for (int i = tid; i < CPB * LDSW; i += 256) acc[i] = 0.f;
    __syncthreads();

    int s = offs[buck], e = offs[buck + 1];
    int base = buck * CPB;
    for (int i = s + wid; i < e; i += 4) {
        int lc = clist[i] - base;              // wave-uniform broadcast
        atomicAdd(&acc[lc * LDSW + lane], sfeat[(size_t)i*C_ + lane]);
    }
    __syncthreads();

    int b = buck / BPB, xy0 = (buck % BPB) * CPB;
    for (int c = 0; c < C_; ++c) {
        for (int j = tid; j < CPB; j += 256) {
            out[((size_t)(b*C_ + c))*(X_*Y_) + xy0 + j] = acc[j * LDSW + c];
        }
    }
}

// Fallback (tiny ws): direct atomics into (B,C,X,Y) output.
__global__ __launch_bounds__(256)
void scatter_fallback(const float* __restrict__ feat,
                      const int* __restrict__ rank,
                      float* __restrict__ dst) {
    int tid  = blockIdx.x * blockDim.x + threadIdx.x;
    int p    = tid >> 6;
    int lane = tid & 63;
    if (p >= NPTS) return;
    int cell = rank[p];
    if (cell < 0) return;
    int b = cell / (X_*Y_);
    int xy = cell % (X_*Y_);
    float v = feat[(size_t)p*C_ + lane];
    unsafeAtomicAdd(&dst[((size_t)(b*C_ + lane))*(X_*Y_) + xy], v);
}

extern "C" void kernel_launch(void* const* d_in, const int* in_sizes, int n_in,
                              void* d_out, int out_size, void* d_ws, size_t ws_size,
                              hipStream_t stream) {
    const float* feat       = (const float*)d_in[0];
    const float* post_trans = (const float*)d_in[1];
    const float* post_rots  = (const float*)d_in[2];
    const float* intr       = (const float*)d_in[3];
    const float* extr       = (const float*)d_in[4];
    const float* frustum    = (const float*)d_in[5];
    const float* bev_res    = (const float*)d_in[6];
    const float* bev_start  = (const float*)d_in[7];
    float* out = (float*)d_out;

    // ws layout
    char* base = (char*)d_ws;
    double* mats = (double*)base;                      size_t off = 4096;
    int* rank    = (int*)(base + off);                 off += (size_t)NPTS*4;
    int* bhist   = (int*)(base + off);                 off += 256*4;
    int* offs    = (int*)(base + off);                 off += 256*4;
    int* cursor  = (int*)(base + off);                 off += 256*4;
    int* clist   = (int*)(base + off);                 off += (size_t)NPTS*4;
    off = (off + 511) & ~(size_t)511;
    float* sfeat = (float*)(base + off);               off += (size_t)NPTS*C_*4; // 88.7 MB
    bool have_ws = (ws_size >= off);

    hipLaunchKernelGGL(prep_kernel, dim3(1), dim3(16), 0, stream,
                       post_rots, intr, extr, mats);

    const int pt_blocks = (NPTS + 255) / 256;
    const int wv_blocks = (int)(((size_t)NPTS*64 + 255) / 256);

    if (have_ws) {
        hipMemsetAsync(bhist, 0, NBUCK*4, stream);
        geom_kernel<<<pt_blocks, 256, 0, stream>>>(post_trans, frustum, bev_res,
                                                   bev_start, mats, rank, bhist);
        scanb_kernel<<<1, 256, 0, stream>>>(bhist, offs, cursor);
        fill3_kernel<<<wv_blocks, 256, 0, stream>>>(feat, rank, cursor, sfeat, clist);
        accum_kernel<<<NBUCK, 256, 0, stream>>>(sfeat, clist, offs, out);
    } else {
        hipMemsetAsync(out, 0, (size_t)out_size*sizeof(float), stream);
        hipMemsetAsync(bhist, 0, NBUCK*4, stream);
        geom_kernel<<<pt_blocks, 256, 0, stream>>>(post_trans, frustum, bev_res,
                                                   bev_start, mats, rank, bhist);
        scatter_fallback<<<wv_blocks, 256, 0, stream>>>(feat, rank, out);
    }
}

// Round 10
// 1722.660 us; speedup vs baseline: 1.3172x; 1.3172x over previous
//
#include <hip/hip_runtime.h>
#include <limits.h>

#define B_ 2
#define N_ 6
#define D_ 41
#define H_ 16
#define W_ 44
#define C_ 64
#define X_ 200
#define Y_ 200
#define NPTS (B_*N_*D_*H_*W_)   // 346368
#define NBN (B_*N_)             // 12
#define NSLICE (NBN*D_)         // 492
#define SPB (N_*D_)             // 246 slices per batch
#define PPS (H_*W_)             // 704 points per slice
#define MAT_STRIDE 24
#define TX 10                   // tile x-cells
#define TY 25                   // tile y-cells
#define TCELLS (TX*TY)          // 250
#define LDSW 65                 // padded accumulator row
#define RSTRIDE 128             // ints per slice in ranges[]

__device__ inline void inv3x3(const double m[9], double out[9]) {
    double a=m[0],b=m[1],c=m[2],d=m[3],e=m[4],f=m[5],g=m[6],h=m[7],i=m[8];
    double A  =  (e*i - f*h);
    double Bm = -(d*i - f*g);
    double Cm =  (d*h - e*g);
    double det = a*A + b*Bm + c*Cm;
    double id = 1.0/det;
    out[0] = A*id;   out[1] = -(b*i - c*h)*id; out[2] =  (b*f - c*e)*id;
    out[3] = Bm*id;  out[4] =  (a*i - c*g)*id; out[5] = -(a*f - c*d)*id;
    out[6] = Cm*id;  out[7] = -(a*h - b*g)*id; out[8] =  (a*e - b*d)*id;
}

// One thread per (b,n): inv(post_rots), comb = rot(inv(extr)) @ inv(K), trans.
__global__ void prep_kernel(const float* __restrict__ post_rots,
                            const float* __restrict__ intr,
                            const float* __restrict__ extr,
                            double* __restrict__ mats) {
    int bn = threadIdx.x;
    if (bn >= NBN) return;

    double pr[9], prinv[9], kk[9], kin[9];
    for (int i=0;i<9;i++) pr[i] = (double)post_rots[bn*9+i];
    inv3x3(pr, prinv);
    for (int i=0;i<9;i++) kk[i] = (double)intr[bn*9+i];
    inv3x3(kk, kin);

    const float* E = extr + bn*16;
    double a00=E[0], a01=E[1], a02=E[2], a03=E[3];
    double a10=E[4], a11=E[5], a12=E[6], a13=E[7];
    double a20=E[8], a21=E[9], a22=E[10], a23=E[11];
    double a30=E[12], a31=E[13], a32=E[14], a33=E[15];

    double s0=a00*a11-a10*a01, s1=a00*a12-a10*a02, s2=a00*a13-a10*a03;
    double s3=a01*a12-a11*a02, s4=a01*a13-a11*a03, s5=a02*a13-a12*a03;
    double c5=a22*a33-a32*a23, c4=a21*a33-a31*a23, c3=a21*a32-a31*a22;
    double c2=a20*a33-a30*a23, c1=a20*a32-a30*a22, c0=a20*a31-a30*a21;
    double det = s0*c5 - s1*c4 + s2*c3 + s3*c2 - s4*c1 + s5*c0;
    double iv = 1.0/det;

    double rot[9], trans[3];
    rot[0] = ( a11*c5 - a12*c4 + a13*c3)*iv;
    rot[1] = (-a01*c5 + a02*c4 - a03*c3)*iv;
    rot[2] = ( a31*s5 - a32*s4 + a33*s3)*iv;
    trans[0]=(-a21*s5 + a22*s4 - a23*s3)*iv;
    rot[3] = (-a10*c5 + a12*c2 - a13*c1)*iv;
    rot[4] = ( a00*c5 - a02*c2 + a03*c1)*iv;
    rot[5] = (-a30*s5 + a32*s2 - a33*s1)*iv;
    trans[1]=( a20*s5 - a22*s2 + a23*s1)*iv;
    rot[6] = ( a10*c4 - a11*c2 + a13*c0)*iv;
    rot[7] = (-a00*c4 + a01*c2 - a03*c0)*iv;
    rot[8] = ( a30*s4 - a31*s2 + a33*s0)*iv;
    trans[2]=(-a20*s4 + a21*s2 - a23*s0)*iv;

    double comb[9];
    for (int i=0;i<3;i++) for (int j=0;j<3;j++)
        comb[i*3+j] = rot[i*3+0]*kin[0+j] + rot[i*3+1]*kin[3+j] + rot[i*3+2]*kin[6+j];

    double* o = mats + (size_t)bn*MAT_STRIDE;
    for (int i=0;i<9;i++) o[i]   = prinv[i];
    for (int i=0;i<9;i++) o[9+i] = comb[i];
    for (int i=0;i<3;i++) o[18+i]= trans[i];
}

// One THREAD per point: cell id (or -1).
__global__ __launch_bounds__(256)
void geom_kernel(const float* __restrict__ post_trans,
                 const float* __restrict__ frustum,
                 const float* __restrict__ bev_res,
                 const float* __restrict__ bev_start,
                 const double* __restrict__ mats,
                 int* __restrict__ rank) {
    int p = blockIdx.x * blockDim.x + threadIdx.x;
    if (p >= NPTS) return;

    int w = p % W_; int t = p / W_;
    int h = t % H_;  t /= H_;
    int d = t % D_;  t /= D_;
    int bn = t;      int b = bn / N_;

    const double* M = mats + (size_t)bn*MAT_STRIDE;
    int fidx = ((d*H_ + h)*W_ + w)*3;
    double fx = (double)frustum[fidx+0];
    double fy = (double)frustum[fidx+1];
    double fz = (double)frustum[fidx+2];

    double px = fx - (double)post_trans[bn*3+0];
    double py = fy - (double)post_trans[bn*3+1];
    double pz = fz - (double)post_trans[bn*3+2];

    double q0 = M[0]*px + M[1]*py + M[2]*pz;
    double q1 = M[3]*px + M[4]*py + M[5]*pz;
    double q2 = M[6]*px + M[7]*py + M[8]*pz;

    double r0 = q0*q2, r1 = q1*q2, r2 = q2;

    double gx = M[9]*r0  + M[10]*r1 + M[11]*r2 + M[18];
    double gy = M[12]*r0 + M[13]*r1 + M[14]*r2 + M[19];
    double gz = M[15]*r0 + M[16]*r1 + M[17]*r2 + M[20];

    double resx = (double)bev_res[0], resy = (double)bev_res[1], resz = (double)bev_res[2];
    double sx = (double)bev_start[0] - resx*0.5;
    double sy = (double)bev_start[1] - resy*0.5;
    double sz = (double)bev_start[2] - resz*0.5;

    int cx = (int)((gx - sx)/resx);
    int cy = (int)((gy - sy)/resy);
    int cz = (int)((gz - sz)/resz);

    int cell = -1;
    if (cx >= 0 && cx < X_ && cy >= 0 && cy < Y_ && cz == 0)
        cell = (b*X_ + cx)*Y_ + cy;
    rank[p] = cell;
}

// Per slice: conservative per-w [cxmin,cxmax] and per-h [cymin,cymax] from rank.
// cxg is the GLOBAL row index (b*X_+cx) so accum can compare without decoding b.
__global__ __launch_bounds__(256)
void ranges_kernel(const int* __restrict__ rank, int* __restrict__ ranges) {
    __shared__ int mn_w[W_], mx_w[W_], mn_h[H_], mx_h[H_];
    int s = blockIdx.x;
    int t = threadIdx.x;
    if (t < W_) { mn_w[t] = INT_MAX; mx_w[t] = -1; }
    if (t < H_) { mn_h[t] = INT_MAX; mx_h[t] = -1; }
    __syncthreads();

    for (int idx = t; idx < PPS; idx += 256) {
        int cell = rank[s*PPS + idx];
        if (cell < 0) continue;
        int w = idx % W_, h = idx / W_;
        int cxg = cell / Y_, cy = cell % Y_;
        atomicMin(&mn_w[w], cxg); atomicMax(&mx_w[w], cxg);
        atomicMin(&mn_h[h], cy);  atomicMax(&mx_h[h], cy);
    }
    __syncthreads();

    int* R = ranges + s*RSTRIDE;
    if (t < W_) { R[t] = mn_w[t]; R[W_ + t] = mx_w[t]; }
    if (t < H_) { R[2*W_ + t] = mn_h[t]; R[2*W_ + H_ + t] = mx_h[t]; }
}

// One block per 10x25 BEV tile. 8 waves split the 246 slices of this batch.
// Per slice: ballot-intersect ranges -> (h,w) subrect; stream rank + feat
// (contiguous along w), ds_add_f32 into padded LDS tile; coalesced out store.
// No global atomics, no random global access, covers every output cell.
__global__ __launch_bounds__(512)
void accum_kernel(const float* __restrict__ feat,
                  const int* __restrict__ rank,
                  const int* __restrict__ ranges,
                  float* __restrict__ out) {
    __shared__ float acc[TCELLS * LDSW];   // 63.5 KiB
    int tx0 = blockIdx.x * TX;
    int ty0 = blockIdx.y * TY;
    int b   = blockIdx.z;
    int tid = threadIdx.x, lane = tid & 63, wave = tid >> 6;

    for (int i = tid; i < TCELLS * LDSW; i += 512) acc[i] = 0.f;
    __syncthreads();

    int gx0 = b*X_ + tx0, gx1 = gx0 + TX - 1;
    int ty1 = ty0 + TY - 1;

    for (int sr = wave; sr < SPB; sr += 8) {
        int s = b*SPB + sr;
        const int* R = ranges + s*RSTRIDE;

        bool okw = false;
        if (lane < W_) {
            int lo = R[lane], hi = R[W_ + lane];
            okw = (hi >= gx0) && (lo <= gx1);
        }
        unsigned long long mw = __ballot(okw);
        if (!mw) continue;

        bool okh = false;
        if (lane < H_) {
            int lo = R[2*W_ + lane], hi = R[2*W_ + H_ + lane];
            okh = (hi >= ty0) && (lo <= ty1);
        }
        unsigned long long mh = __ballot(okh);
        if (!mh) continue;

        int wmin = __ffsll(mw) - 1, wmax = 63 - __clzll(mw);
        int hmin = __ffsll(mh) - 1, hmax = 63 - __clzll(mh);

        for (int h = hmin; h <= hmax; ++h) {
            int pbase = s*PPS + h*W_;
            for (int w = wmin; w <= wmax; ++w) {
                int cell = rank[pbase + w];
                if (cell < 0) continue;
                int cxg = cell / Y_, cy = cell % Y_;
                if (cxg < gx0 || cxg > gx1 || cy < ty0 || cy > ty1) continue;
                int lc = (cxg - gx0)*TY + (cy - ty0);
                atomicAdd(&acc[lc*LDSW + lane], feat[(size_t)(pbase + w)*C_ + lane]);
            }
        }
    }
    __syncthreads();

    // out (B,C,X,Y), coalesced-ish: runs of TY consecutive y per (c, x).
    for (int idx = tid; idx < C_*TCELLS; idx += 512) {
        int c = idx / TCELLS, lc = idx % TCELLS;
        int x = lc / TY, y = lc % TY;
        out[((size_t)(b*C_ + c))*(X_*Y_) + (tx0 + x)*Y_ + ty0 + y] = acc[lc*LDSW + c];
    }
}

// Fallback (tiny ws): direct atomics into (B,C,X,Y) output.
__global__ __launch_bounds__(256)
void scatter_fallback(const float* __restrict__ feat,
                      const int* __restrict__ rank,
                      float* __restrict__ dst) {
    int tid  = blockIdx.x * blockDim.x + threadIdx.x;
    int p    = tid >> 6;
    int lane = tid & 63;
    if (p >= NPTS) return;
    int cell = rank[p];
    if (cell < 0) return;
    int b = cell / (X_*Y_);
    int xy = cell % (X_*Y_);
    float v = feat[(size_t)p*C_ + lane];
    unsafeAtomicAdd(&dst[((size_t)(b*C_ + lane))*(X_*Y_) + xy], v);
}

extern "C" void kernel_launch(void* const* d_in, const int* in_sizes, int n_in,
                              void* d_out, int out_size, void* d_ws, size_t ws_size,
                              hipStream_t stream) {
    const float* feat       = (const float*)d_in[0];
    const float* post_trans = (const float*)d_in[1];
    const float* post_rots  = (const float*)d_in[2];
    const float* intr       = (const float*)d_in[3];
    const float* extr       = (const float*)d_in[4];
    const float* frustum    = (const float*)d_in[5];
    const float* bev_res    = (const float*)d_in[6];
    const float* bev_start  = (const float*)d_in[7];
    float* out = (float*)d_out;

    // ws layout (tiny now: ~1.7 MB)
    char* base = (char*)d_ws;
    double* mats = (double*)base;                      size_t off = 4096;
    int* rank    = (int*)(base + off);                 off += (size_t)NPTS*4;
    int* ranges  = (int*)(base + off);                 off += (size_t)NSLICE*RSTRIDE*4;
    bool have_ws = (ws_size >= off);

    hipLaunchKernelGGL(prep_kernel, dim3(1), dim3(16), 0, stream,
                       post_rots, intr, extr, mats);

    const int pt_blocks = (NPTS + 255) / 256;

    geom_kernel<<<pt_blocks, 256, 0, stream>>>(post_trans, frustum, bev_res,
                                               bev_start, mats, rank);

    if (have_ws) {
        ranges_kernel<<<NSLICE, 256, 0, stream>>>(rank, ranges);
        accum_kernel<<<dim3(X_/TX, Y_/TY, B_), 512, 0, stream>>>(feat, rank, ranges, out);
    } else {
        hipMemsetAsync(out, 0, (size_t)out_size*sizeof(float), stream);
        const int wv_blocks = (int)(((size_t)NPTS*64 + 255) / 256);
        scatter_fallback<<<wv_blocks, 256, 0, stream>>>(feat, rank, out);
    }
}

// Round 11
// 105.685 us; speedup vs baseline: 21.4696x; 16.2999x over previous
//
#include <hip/hip_runtime.h>
#include <hip/hip_fp16.h>

#define B_ 2
#define N_ 6
#define D_ 41
#define H_ 16
#define W_ 44
#define C_ 64
#define X_ 200
#define Y_ 200
#define NPTS (B_*N_*D_*H_*W_)   // 346368
#define NBN (B_*N_)             // 12
#define NCELL (B_*X_*Y_)        // 80000
#define MAT_STRIDE 24

// Deterministic HW packed-fp16 atomic add (gfx90a+/gfx950): 2 channels per op.
__device__ inline void pk_add_f16(__half2* addr, __half2 val) {
    unsigned int u = *reinterpret_cast<unsigned int*>(&val);
    asm volatile("global_atomic_pk_add_f16 %0, %1, off"
                 :: "v"((unsigned long long)(uintptr_t)addr), "v"(u)
                 : "memory");
}

__device__ inline void inv3x3(const double m[9], double out[9]) {
    double a=m[0],b=m[1],c=m[2],d=m[3],e=m[4],f=m[5],g=m[6],h=m[7],i=m[8];
    double A  =  (e*i - f*h);
    double Bm = -(d*i - f*g);
    double Cm =  (d*h - e*g);
    double det = a*A + b*Bm + c*Cm;
    double id = 1.0/det;
    out[0] = A*id;   out[1] = -(b*i - c*h)*id; out[2] =  (b*f - c*e)*id;
    out[3] = Bm*id;  out[4] =  (a*i - c*g)*id; out[5] = -(a*f - c*d)*id;
    out[6] = Cm*id;  out[7] = -(a*h - b*g)*id; out[8] =  (a*e - b*d)*id;
}

// One thread per (b,n): inv(post_rots), comb = rot(inv(extr)) @ inv(K), trans.
__global__ void prep_kernel(const float* __restrict__ post_rots,
                            const float* __restrict__ intr,
                            const float* __restrict__ extr,
                            double* __restrict__ mats) {
    int bn = threadIdx.x;
    if (bn >= NBN) return;

    double pr[9], prinv[9], kk[9], kin[9];
    for (int i=0;i<9;i++) pr[i] = (double)post_rots[bn*9+i];
    inv3x3(pr, prinv);
    for (int i=0;i<9;i++) kk[i] = (double)intr[bn*9+i];
    inv3x3(kk, kin);

    const float* E = extr + bn*16;
    double a00=E[0], a01=E[1], a02=E[2], a03=E[3];
    double a10=E[4], a11=E[5], a12=E[6], a13=E[7];
    double a20=E[8], a21=E[9], a22=E[10], a23=E[11];
    double a30=E[12], a31=E[13], a32=E[14], a33=E[15];

    double s0=a00*a11-a10*a01, s1=a00*a12-a10*a02, s2=a00*a13-a10*a03;
    double s3=a01*a12-a11*a02, s4=a01*a13-a11*a03, s5=a02*a13-a12*a03;
    double c5=a22*a33-a32*a23, c4=a21*a33-a31*a23, c3=a21*a32-a31*a22;
    double c2=a20*a33-a30*a23, c1=a20*a32-a30*a22, c0=a20*a31-a30*a21;
    double det = s0*c5 - s1*c4 + s2*c3 + s3*c2 - s4*c1 + s5*c0;
    double iv = 1.0/det;

    double rot[9], trans[3];
    rot[0] = ( a11*c5 - a12*c4 + a13*c3)*iv;
    rot[1] = (-a01*c5 + a02*c4 - a03*c3)*iv;
    rot[2] = ( a31*s5 - a32*s4 + a33*s3)*iv;
    trans[0]=(-a21*s5 + a22*s4 - a23*s3)*iv;
    rot[3] = (-a10*c5 + a12*c2 - a13*c1)*iv;
    rot[4] = ( a00*c5 - a02*c2 + a03*c1)*iv;
    rot[5] = (-a30*s5 + a32*s2 - a33*s1)*iv;
    trans[1]=( a20*s5 - a22*s2 + a23*s1)*iv;
    rot[6] = ( a10*c4 - a11*c2 + a13*c0)*iv;
    rot[7] = (-a00*c4 + a01*c2 - a03*c0)*iv;
    rot[8] = ( a30*s4 - a31*s2 + a33*s0)*iv;
    trans[2]=(-a20*s4 + a21*s2 - a23*s0)*iv;

    double comb[9];
    for (int i=0;i<3;i++) for (int j=0;j<3;j++)
        comb[i*3+j] = rot[i*3+0]*kin[0+j] + rot[i*3+1]*kin[3+j] + rot[i*3+2]*kin[6+j];

    double* o = mats + (size_t)bn*MAT_STRIDE;
    for (int i=0;i<9;i++) o[i]   = prinv[i];
    for (int i=0;i<9;i++) o[9+i] = comb[i];
    for (int i=0;i<3;i++) o[18+i]= trans[i];
}

// One THREAD per point: cell id (or -1).
__global__ __launch_bounds__(256)
void geom_kernel(const float* __restrict__ post_trans,
                 const float* __restrict__ frustum,
                 const float* __restrict__ bev_res,
                 const float* __restrict__ bev_start,
                 const double* __restrict__ mats,
                 int* __restrict__ rank) {
    int p = blockIdx.x * blockDim.x + threadIdx.x;
    if (p >= NPTS) return;

    int w = p % W_; int t = p / W_;
    int h = t % H_;  t /= H_;
    int d = t % D_;  t /= D_;
    int bn = t;      int b = bn / N_;

    const double* M = mats + (size_t)bn*MAT_STRIDE;
    int fidx = ((d*H_ + h)*W_ + w)*3;
    double fx = (double)frustum[fidx+0];
    double fy = (double)frustum[fidx+1];
    double fz = (double)frustum[fidx+2];

    double px = fx - (double)post_trans[bn*3+0];
    double py = fy - (double)post_trans[bn*3+1];
    double pz = fz - (double)post_trans[bn*3+2];

    double q0 = M[0]*px + M[1]*py + M[2]*pz;
    double q1 = M[3]*px + M[4]*py + M[5]*pz;
    double q2 = M[6]*px + M[7]*py + M[8]*pz;

    double r0 = q0*q2, r1 = q1*q2, r2 = q2;

    double gx = M[9]*r0  + M[10]*r1 + M[11]*r2 + M[18];
    double gy = M[12]*r0 + M[13]*r1 + M[14]*r2 + M[19];
    double gz = M[15]*r0 + M[16]*r1 + M[17]*r2 + M[20];

    double resx = (double)bev_res[0], resy = (double)bev_res[1], resz = (double)bev_res[2];
    double sx = (double)bev_start[0] - resx*0.5;
    double sy = (double)bev_start[1] - resy*0.5;
    double sz = (double)bev_start[2] - resz*0.5;

    int cx = (int)((gx - sx)/resx);
    int cy = (int)((gy - sy)/resy);
    int cz = (int)((gz - sz)/resz);

    int cell = -1;
    if (cx >= 0 && cx < X_ && cy >= 0 && cy < Y_ && cz == 0)
        cell = (b*X_ + cx)*Y_ + cy;
    rank[p] = cell;
}

// Two points per wave (lanes 0-31 / 32-63); lane handles 2 channels.
// feat read sequential (float2, coalesced); 32 pk-f16 atomics per point
// = 128B = 2 cache lines per point (half of R7's f32 scatter).
__global__ __launch_bounds__(256)
void scatter_h2(const float2* __restrict__ feat2,
                const int* __restrict__ rank,
                __half2* __restrict__ stage) {
    int tid  = blockIdx.x * blockDim.x + threadIdx.x;
    int pp   = tid >> 6;
    int lane = tid & 63;
    int p    = pp*2 + (lane >> 5);
    int k    = lane & 31;
    if (p >= NPTS) return;
    int cell = rank[p];
    if (cell < 0) return;
    float2 v = feat2[(size_t)p*32 + k];
    __half2 h;
    h.x = __float2half(v.x);
    h.y = __float2half(v.y);
    pk_add_f16(&stage[(size_t)cell*32 + k], h);
}

// (B, X*Y, C) fp16 stage -> (B, C, X*Y) f32 output.
__global__ __launch_bounds__(512)
void trans_h2(const __half2* __restrict__ stage, float* __restrict__ out) {
    __shared__ float tile[64][65];
    int b   = blockIdx.y;
    int xy0 = blockIdx.x * 64;
    int tx  = threadIdx.x & 31;    // half2 index (channel pair)
    int ty  = threadIdx.x >> 5;    // 0..15

    #pragma unroll
    for (int i = 0; i < 4; ++i) {
        int r = ty + i*16;         // 0..63
        __half2 v = stage[((size_t)b*(X_*Y_) + xy0 + r)*32 + tx];
        float2 f = __half22float2(v);
        tile[r][2*tx]   = f.x;
        tile[r][2*tx+1] = f.y;
    }
    __syncthreads();
    int cw = threadIdx.x >> 6;     // 0..7
    int j  = threadIdx.x & 63;
    #pragma unroll
    for (int k = 0; k < 8; ++k) {
        int c = cw*8 + k;
        out[((size_t)(b*C_ + c))*(X_*Y_) + xy0 + j] = tile[j][c];
    }
}

// Fallback (tiny ws): direct f32 atomics into (B,C,X,Y) output.
__global__ __launch_bounds__(256)
void scatter_fallback(const float* __restrict__ feat,
                      const int* __restrict__ rank,
                      float* __restrict__ dst) {
    int tid  = blockIdx.x * blockDim.x + threadIdx.x;
    int p    = tid >> 6;
    int lane = tid & 63;
    if (p >= NPTS) return;
    int cell = rank[p];
    if (cell < 0) return;
    int b = cell / (X_*Y_);
    int xy = cell % (X_*Y_);
    float v = feat[(size_t)p*C_ + lane];
    unsafeAtomicAdd(&dst[((size_t)(b*C_ + lane))*(X_*Y_) + xy], v);
}

extern "C" void kernel_launch(void* const* d_in, const int* in_sizes, int n_in,
                              void* d_out, int out_size, void* d_ws, size_t ws_size,
                              hipStream_t stream) {
    const float* feat       = (const float*)d_in[0];
    const float* post_trans = (const float*)d_in[1];
    const float* post_rots  = (const float*)d_in[2];
    const float* intr       = (const float*)d_in[3];
    const float* extr       = (const float*)d_in[4];
    const float* frustum    = (const float*)d_in[5];
    const float* bev_res    = (const float*)d_in[6];
    const float* bev_start  = (const float*)d_in[7];
    float* out = (float*)d_out;

    // ws layout
    char* base = (char*)d_ws;
    double* mats   = (double*)base;                    size_t off = 4096;
    int* rank      = (int*)(base + off);               off += (size_t)NPTS*4;
    off = (off + 511) & ~(size_t)511;
    __half2* stage = (__half2*)(base + off);           off += (size_t)NCELL*C_*2; // 10.24 MB
    bool have_ws = (ws_size >= off);

    hipLaunchKernelGGL(prep_kernel, dim3(1), dim3(16), 0, stream,
                       post_rots, intr, extr, mats);

    const int pt_blocks = (NPTS + 255) / 256;

    geom_kernel<<<pt_blocks, 256, 0, stream>>>(post_trans, frustum, bev_res,
                                               bev_start, mats, rank);

    if (have_ws) {
        hipMemsetAsync(stage, 0, (size_t)NCELL*C_*2, stream);
        const int sc_blocks = (int)(((size_t)(NPTS/2)*64 + 255) / 256);  // 43296
        scatter_h2<<<sc_blocks, 256, 0, stream>>>((const float2*)feat, rank, stage);
        trans_h2<<<dim3((X_*Y_)/64, B_), 512, 0, stream>>>(stage, out);
    } else {
        hipMemsetAsync(out, 0, (size_t)out_size*sizeof(float), stream);
        const int wv_blocks = (int)(((size_t)NPTS*64 + 255) / 256);
        scatter_fallback<<<wv_blocks, 256, 0, stream>>>(feat, rank, out);
    }
}

// Round 12
// 77.517 us; speedup vs baseline: 29.2714x; 1.3634x over previous
//
#include <hip/hip_runtime.h>
#include <hip/hip_fp16.h>

#define B_ 2
#define N_ 6
#define D_ 41
#define H_ 16
#define W_ 44
#define C_ 64
#define X_ 200
#define Y_ 200
#define NPTS (B_*N_*D_*H_*W_)   // 346368
#define NBN (B_*N_)             // 12
#define NCELL (B_*X_*Y_)        // 80000
#define MAT_STRIDE 24
#define KREP 4                  // stage replicas (hot-line contention / KREP)

// Deterministic HW packed-fp16 atomic add (gfx90a+/gfx950): 2 channels per op.
__device__ inline void pk_add_f16(__half2* addr, __half2 val) {
    unsigned int u = *reinterpret_cast<unsigned int*>(&val);
    asm volatile("global_atomic_pk_add_f16 %0, %1, off"
                 :: "v"((unsigned long long)(uintptr_t)addr), "v"(u)
                 : "memory");
}

__device__ inline void inv3x3(const double m[9], double out[9]) {
    double a=m[0],b=m[1],c=m[2],d=m[3],e=m[4],f=m[5],g=m[6],h=m[7],i=m[8];
    double A  =  (e*i - f*h);
    double Bm = -(d*i - f*g);
    double Cm =  (d*h - e*g);
    double det = a*A + b*Bm + c*Cm;
    double id = 1.0/det;
    out[0] = A*id;   out[1] = -(b*i - c*h)*id; out[2] =  (b*f - c*e)*id;
    out[3] = Bm*id;  out[4] =  (a*i - c*g)*id; out[5] = -(a*f - c*d)*id;
    out[6] = Cm*id;  out[7] = -(a*h - b*g)*id; out[8] =  (a*e - b*d)*id;
}

// One thread per (b,n): inv(post_rots), comb = rot(inv(extr)) @ inv(K), trans.
__global__ void prep_kernel(const float* __restrict__ post_rots,
                            const float* __restrict__ intr,
                            const float* __restrict__ extr,
                            double* __restrict__ mats) {
    int bn = threadIdx.x;
    if (bn >= NBN) return;

    double pr[9], prinv[9], kk[9], kin[9];
    for (int i=0;i<9;i++) pr[i] = (double)post_rots[bn*9+i];
    inv3x3(pr, prinv);
    for (int i=0;i<9;i++) kk[i] = (double)intr[bn*9+i];
    inv3x3(kk, kin);

    const float* E = extr + bn*16;
    double a00=E[0], a01=E[1], a02=E[2], a03=E[3];
    double a10=E[4], a11=E[5], a12=E[6], a13=E[7];
    double a20=E[8], a21=E[9], a22=E[10], a23=E[11];
    double a30=E[12], a31=E[13], a32=E[14], a33=E[15];

    double s0=a00*a11-a10*a01, s1=a00*a12-a10*a02, s2=a00*a13-a10*a03;
    double s3=a01*a12-a11*a02, s4=a01*a13-a11*a03, s5=a02*a13-a12*a03;
    double c5=a22*a33-a32*a23, c4=a21*a33-a31*a23, c3=a21*a32-a31*a22;
    double c2=a20*a33-a30*a23, c1=a20*a32-a30*a22, c0=a20*a31-a30*a21;
    double det = s0*c5 - s1*c4 + s2*c3 + s3*c2 - s4*c1 + s5*c0;
    double iv = 1.0/det;

    double rot[9], trans[3];
    rot[0] = ( a11*c5 - a12*c4 + a13*c3)*iv;
    rot[1] = (-a01*c5 + a02*c4 - a03*c3)*iv;
    rot[2] = ( a31*s5 - a32*s4 + a33*s3)*iv;
    trans[0]=(-a21*s5 + a22*s4 - a23*s3)*iv;
    rot[3] = (-a10*c5 + a12*c2 - a13*c1)*iv;
    rot[4] = ( a00*c5 - a02*c2 + a03*c1)*iv;
    rot[5] = (-a30*s5 + a32*s2 - a33*s1)*iv;
    trans[1]=( a20*s5 - a22*s2 + a23*s1)*iv;
    rot[6] = ( a10*c4 - a11*c2 + a13*c0)*iv;
    rot[7] = (-a00*c4 + a01*c2 - a03*c0)*iv;
    rot[8] = ( a30*s4 - a31*s2 + a33*s0)*iv;
    trans[2]=(-a20*s4 + a21*s2 - a23*s0)*iv;

    double comb[9];
    for (int i=0;i<3;i++) for (int j=0;j<3;j++)
        comb[i*3+j] = rot[i*3+0]*kin[0+j] + rot[i*3+1]*kin[3+j] + rot[i*3+2]*kin[6+j];

    double* o = mats + (size_t)bn*MAT_STRIDE;
    for (int i=0;i<9;i++) o[i]   = prinv[i];
    for (int i=0;i<9;i++) o[9+i] = comb[i];
    for (int i=0;i<3;i++) o[18+i]= trans[i];
}

// One THREAD per point: cell id (or -1).
__global__ __launch_bounds__(256)
void geom_kernel(const float* __restrict__ post_trans,
                 const float* __restrict__ frustum,
                 const float* __restrict__ bev_res,
                 const float* __restrict__ bev_start,
                 const double* __restrict__ mats,
                 int* __restrict__ rank) {
    int p = blockIdx.x * blockDim.x + threadIdx.x;
    if (p >= NPTS) return;

    int w = p % W_; int t = p / W_;
    int h = t % H_;  t /= H_;
    int d = t % D_;  t /= D_;
    int bn = t;      int b = bn / N_;

    const double* M = mats + (size_t)bn*MAT_STRIDE;
    int fidx = ((d*H_ + h)*W_ + w)*3;
    double fx = (double)frustum[fidx+0];
    double fy = (double)frustum[fidx+1];
    double fz = (double)frustum[fidx+2];

    double px = fx - (double)post_trans[bn*3+0];
    double py = fy - (double)post_trans[bn*3+1];
    double pz = fz - (double)post_trans[bn*3+2];

    double q0 = M[0]*px + M[1]*py + M[2]*pz;
    double q1 = M[3]*px + M[4]*py + M[5]*pz;
    double q2 = M[6]*px + M[7]*py + M[8]*pz;

    double r0 = q0*q2, r1 = q1*q2, r2 = q2;

    double gx = M[9]*r0  + M[10]*r1 + M[11]*r2 + M[18];
    double gy = M[12]*r0 + M[13]*r1 + M[14]*r2 + M[19];
    double gz = M[15]*r0 + M[16]*r1 + M[17]*r2 + M[20];

    double resx = (double)bev_res[0], resy = (double)bev_res[1], resz = (double)bev_res[2];
    double sx = (double)bev_start[0] - resx*0.5;
    double sy = (double)bev_start[1] - resy*0.5;
    double sz = (double)bev_start[2] - resz*0.5;

    int cx = (int)((gx - sx)/resx);
    int cy = (int)((gy - sy)/resy);
    int cz = (int)((gz - sz)/resz);

    int cell = -1;
    if (cx >= 0 && cx < X_ && cy >= 0 && cy < Y_ && cz == 0)
        cell = (b*X_ + cx)*Y_ + cy;
    rank[p] = cell;
}

// Two points per wave (lanes 0-31 / 32-63); lane handles 2 channels (half2).
// Replica = pp&3 spreads hot-cell contributors over 4 stages (contention /4).
// Intra-wave merge: if both points share a cell, fold odd half into even half.
__global__ __launch_bounds__(256)
void scatter_h2(const float2* __restrict__ feat2,
                const int* __restrict__ rank,
                __half2* __restrict__ stage) {
    int tid  = blockIdx.x * blockDim.x + threadIdx.x;
    int pp   = tid >> 6;
    int lane = tid & 63;
    int p    = pp*2 + (lane >> 5);
    int k    = lane & 31;

    bool valid = (p < NPTS);
    int cell = valid ? rank[p] : -1;      // wave-uniform per half
    float2 v = make_float2(0.f, 0.f);
    if (cell >= 0) v = feat2[(size_t)p*32 + k];

    // exchange with partner half (all lanes participate)
    int   ocell = __shfl_xor(cell, 32);
    float ox    = __shfl_xor(v.x, 32);
    float oy    = __shfl_xor(v.y, 32);

    if (cell >= 0 && cell == ocell) {
        if (lane < 32) { v.x += ox; v.y += oy; }
        else cell = -1;                   // odd half merged away
    }
    if (cell < 0) return;

    __half2 h;
    h.x = __float2half(v.x);
    h.y = __float2half(v.y);
    __half2* rep = stage + (size_t)(pp & (KREP-1)) * ((size_t)NCELL*32);
    pk_add_f16(&rep[(size_t)cell*32 + k], h);
}

// Sum 4 fp16 replicas (B, X*Y, C) -> (B, C, X*Y) f32 output.
__global__ __launch_bounds__(512)
void trans_h2(const __half2* __restrict__ stage, float* __restrict__ out) {
    __shared__ float tile[64][65];
    int b   = blockIdx.y;
    int xy0 = blockIdx.x * 64;
    int tx  = threadIdx.x & 31;    // half2 index (channel pair)
    int ty  = threadIdx.x >> 5;    // 0..15

    const size_t rstride = (size_t)NCELL*32;
    #pragma unroll
    for (int i = 0; i < 4; ++i) {
        int r = ty + i*16;         // 0..63
        size_t idx = ((size_t)b*(X_*Y_) + xy0 + r)*32 + tx;
        float sx = 0.f, sy = 0.f;
        #pragma unroll
        for (int kk = 0; kk < KREP; ++kk) {
            float2 f = __half22float2(stage[kk*rstride + idx]);
            sx += f.x; sy += f.y;
        }
        tile[r][2*tx]   = sx;
        tile[r][2*tx+1] = sy;
    }
    __syncthreads();
    int cw = threadIdx.x >> 6;     // 0..7
    int j  = threadIdx.x & 63;
    #pragma unroll
    for (int k = 0; k < 8; ++k) {
        int c = cw*8 + k;
        out[((size_t)(b*C_ + c))*(X_*Y_) + xy0 + j] = tile[j][c];
    }
}

// Fallback (tiny ws): direct f32 atomics into (B,C,X,Y) output.
__global__ __launch_bounds__(256)
void scatter_fallback(const float* __restrict__ feat,
                      const int* __restrict__ rank,
                      float* __restrict__ dst) {
    int tid  = blockIdx.x * blockDim.x + threadIdx.x;
    int p    = tid >> 6;
    int lane = tid & 63;
    if (p >= NPTS) return;
    int cell = rank[p];
    if (cell < 0) return;
    int b = cell / (X_*Y_);
    int xy = cell % (X_*Y_);
    float v = feat[(size_t)p*C_ + lane];
    unsafeAtomicAdd(&dst[((size_t)(b*C_ + lane))*(X_*Y_) + xy], v);
}

extern "C" void kernel_launch(void* const* d_in, const int* in_sizes, int n_in,
                              void* d_out, int out_size, void* d_ws, size_t ws_size,
                              hipStream_t stream) {
    const float* feat       = (const float*)d_in[0];
    const float* post_trans = (const float*)d_in[1];
    const float* post_rots  = (const float*)d_in[2];
    const float* intr       = (const float*)d_in[3];
    const float* extr       = (const float*)d_in[4];
    const float* frustum    = (const float*)d_in[5];
    const float* bev_res    = (const float*)d_in[6];
    const float* bev_start  = (const float*)d_in[7];
    float* out = (float*)d_out;

    // ws layout
    char* base = (char*)d_ws;
    double* mats   = (double*)base;                    size_t off = 4096;
    int* rank      = (int*)(base + off);               off += (size_t)NPTS*4;
    off = (off + 511) & ~(size_t)511;
    __half2* stage = (__half2*)(base + off);
    const size_t stage_bytes = (size_t)KREP * NCELL * C_ * 2;  // 40.96 MB
    off += stage_bytes;
    bool have_ws = (ws_size >= off);

    hipLaunchKernelGGL(prep_kernel, dim3(1), dim3(16), 0, stream,
                       post_rots, intr, extr, mats);

    const int pt_blocks = (NPTS + 255) / 256;

    geom_kernel<<<pt_blocks, 256, 0, stream>>>(post_trans, frustum, bev_res,
                                               bev_start, mats, rank);

    if (have_ws) {
        hipMemsetAsync(stage, 0, stage_bytes, stream);
        const int sc_blocks = (int)(((size_t)(NPTS/2)*64 + 255) / 256);  // 43296
        scatter_h2<<<sc_blocks, 256, 0, stream>>>((const float2*)feat, rank, stage);
        trans_h2<<<dim3((X_*Y_)/64, B_), 512, 0, stream>>>(stage, out);
    } else {
        hipMemsetAsync(out, 0, (size_t)out_size*sizeof(float), stream);
        const int wv_blocks = (int)(((size_t)NPTS*64 + 255) / 256);
        scatter_fallback<<<wv_blocks, 256, 0, stream>>>(feat, rank, out);
    }
}

// Round 13
// 77.012 us; speedup vs baseline: 29.4632x; 1.0066x over previous
//
#include <hip/hip_runtime.h>
#include <hip/hip_fp16.h>

#define B_ 2
#define N_ 6
#define D_ 41
#define H_ 16
#define W_ 44
#define C_ 64
#define X_ 200
#define Y_ 200
#define NPTS (B_*N_*D_*H_*W_)   // 346368 (multiple of 4)
#define NBN (B_*N_)             // 12
#define NCELL (B_*X_*Y_)        // 80000
#define MAT_STRIDE 24
#define KREP 4                  // stage replicas (hot-line contention / KREP)

// Deterministic HW packed-fp16 atomic add (gfx90a+/gfx950): 2 channels per op.
__device__ inline void pk_add_f16(__half2* addr, __half2 val) {
    unsigned int u = *reinterpret_cast<unsigned int*>(&val);
    asm volatile("global_atomic_pk_add_f16 %0, %1, off"
                 :: "v"((unsigned long long)(uintptr_t)addr), "v"(u)
                 : "memory");
}

__device__ inline void inv3x3(const double m[9], double out[9]) {
    double a=m[0],b=m[1],c=m[2],d=m[3],e=m[4],f=m[5],g=m[6],h=m[7],i=m[8];
    double A  =  (e*i - f*h);
    double Bm = -(d*i - f*g);
    double Cm =  (d*h - e*g);
    double det = a*A + b*Bm + c*Cm;
    double id = 1.0/det;
    out[0] = A*id;   out[1] = -(b*i - c*h)*id; out[2] =  (b*f - c*e)*id;
    out[3] = Bm*id;  out[4] =  (a*i - c*g)*id; out[5] = -(a*f - c*d)*id;
    out[6] = Cm*id;  out[7] = -(a*h - b*g)*id; out[8] =  (a*e - b*d)*id;
}

// One thread per (b,n): inv(post_rots), comb = rot(inv(extr)) @ inv(K), trans.
__global__ void prep_kernel(const float* __restrict__ post_rots,
                            const float* __restrict__ intr,
                            const float* __restrict__ extr,
                            double* __restrict__ mats) {
    int bn = threadIdx.x;
    if (bn >= NBN) return;

    double pr[9], prinv[9], kk[9], kin[9];
    for (int i=0;i<9;i++) pr[i] = (double)post_rots[bn*9+i];
    inv3x3(pr, prinv);
    for (int i=0;i<9;i++) kk[i] = (double)intr[bn*9+i];
    inv3x3(kk, kin);

    const float* E = extr + bn*16;
    double a00=E[0], a01=E[1], a02=E[2], a03=E[3];
    double a10=E[4], a11=E[5], a12=E[6], a13=E[7];
    double a20=E[8], a21=E[9], a22=E[10], a23=E[11];
    double a30=E[12], a31=E[13], a32=E[14], a33=E[15];

    double s0=a00*a11-a10*a01, s1=a00*a12-a10*a02, s2=a00*a13-a10*a03;
    double s3=a01*a12-a11*a02, s4=a01*a13-a11*a03, s5=a02*a13-a12*a03;
    double c5=a22*a33-a32*a23, c4=a21*a33-a31*a23, c3=a21*a32-a31*a22;
    double c2=a20*a33-a30*a23, c1=a20*a32-a30*a22, c0=a20*a31-a30*a21;
    double det = s0*c5 - s1*c4 + s2*c3 + s3*c2 - s4*c1 + s5*c0;
    double iv = 1.0/det;

    double rot[9], trans[3];
    rot[0] = ( a11*c5 - a12*c4 + a13*c3)*iv;
    rot[1] = (-a01*c5 + a02*c4 - a03*c3)*iv;
    rot[2] = ( a31*s5 - a32*s4 + a33*s3)*iv;
    trans[0]=(-a21*s5 + a22*s4 - a23*s3)*iv;
    rot[3] = (-a10*c5 + a12*c2 - a13*c1)*iv;
    rot[4] = ( a00*c5 - a02*c2 + a03*c1)*iv;
    rot[5] = (-a30*s5 + a32*s2 - a33*s1)*iv;
    trans[1]=( a20*s5 - a22*s2 + a23*s1)*iv;
    rot[6] = ( a10*c4 - a11*c2 + a13*c0)*iv;
    rot[7] = (-a00*c4 + a01*c2 - a03*c0)*iv;
    rot[8] = ( a30*s4 - a31*s2 + a33*s0)*iv;
    trans[2]=(-a20*s4 + a21*s2 - a23*s0)*iv;

    double comb[9];
    for (int i=0;i<3;i++) for (int j=0;j<3;j++)
        comb[i*3+j] = rot[i*3+0]*kin[0+j] + rot[i*3+1]*kin[3+j] + rot[i*3+2]*kin[6+j];

    double* o = mats + (size_t)bn*MAT_STRIDE;
    for (int i=0;i<9;i++) o[i]   = prinv[i];
    for (int i=0;i<9;i++) o[9+i] = comb[i];
    for (int i=0;i<3;i++) o[18+i]= trans[i];
}

// One THREAD per point: cell id (or -1).
__global__ __launch_bounds__(256)
void geom_kernel(const float* __restrict__ post_trans,
                 const float* __restrict__ frustum,
                 const float* __restrict__ bev_res,
                 const float* __restrict__ bev_start,
                 const double* __restrict__ mats,
                 int* __restrict__ rank) {
    int p = blockIdx.x * blockDim.x + threadIdx.x;
    if (p >= NPTS) return;

    int w = p % W_; int t = p / W_;
    int h = t % H_;  t /= H_;
    int d = t % D_;  t /= D_;
    int bn = t;      int b = bn / N_;

    const double* M = mats + (size_t)bn*MAT_STRIDE;
    int fidx = ((d*H_ + h)*W_ + w)*3;
    double fx = (double)frustum[fidx+0];
    double fy = (double)frustum[fidx+1];
    double fz = (double)frustum[fidx+2];

    double px = fx - (double)post_trans[bn*3+0];
    double py = fy - (double)post_trans[bn*3+1];
    double pz = fz - (double)post_trans[bn*3+2];

    double q0 = M[0]*px + M[1]*py + M[2]*pz;
    double q1 = M[3]*px + M[4]*py + M[5]*pz;
    double q2 = M[6]*px + M[7]*py + M[8]*pz;

    double r0 = q0*q2, r1 = q1*q2, r2 = q2;

    double gx = M[9]*r0  + M[10]*r1 + M[11]*r2 + M[18];
    double gy = M[12]*r0 + M[13]*r1 + M[14]*r2 + M[19];
    double gz = M[15]*r0 + M[16]*r1 + M[17]*r2 + M[20];

    double resx = (double)bev_res[0], resy = (double)bev_res[1], resz = (double)bev_res[2];
    double sx = (double)bev_start[0] - resx*0.5;
    double sy = (double)bev_start[1] - resy*0.5;
    double sz = (double)bev_start[2] - resz*0.5;

    int cx = (int)((gx - sx)/resx);
    int cy = (int)((gy - sy)/resy);
    int cz = (int)((gz - sz)/resz);

    int cell = -1;
    if (cx >= 0 && cx < X_ && cy >= 0 && cy < Y_ && cz == 0)
        cell = (b*X_ + cx)*Y_ + cy;
    rank[p] = cell;
}

// Four consecutive points per wave (2 iters x 2 halves); lane = channel pair.
// Run-merge: pairwise via shfl_xor(32) within each iter, then cross-iter in
// registers (f32). Aligned runs of 2/4 collapse to fewer pk-f16 atomics.
// Replica = q&3 spreads hot-cell contributors across 4 stages.
__global__ __launch_bounds__(256)
void scatter_h4(const float2* __restrict__ feat2,
                const int* __restrict__ rank,
                __half2* __restrict__ stage) {
    int tid  = blockIdx.x * blockDim.x + threadIdx.x;
    int q    = tid >> 6;            // wave id -> points 4q..4q+3
    int lane = tid & 63;
    int half = lane >> 5;
    int k    = lane & 31;
    int p0   = q * 4;
    if (p0 >= NPTS) return;         // NPTS % 4 == 0: wave-uniform exit

    int cA = rank[p0 + half];
    int cB = rank[p0 + 2 + half];
    float2 vA = make_float2(0.f, 0.f), vB = make_float2(0.f, 0.f);
    if (cA >= 0) vA = feat2[(size_t)(p0 + half)*32 + k];
    if (cB >= 0) vB = feat2[(size_t)(p0 + 2 + half)*32 + k];

    // pair merge within A (p0 <- p1)
    int   oc = __shfl_xor(cA, 32);
    float ox = __shfl_xor(vA.x, 32), oy = __shfl_xor(vA.y, 32);
    if (cA >= 0 && cA == oc) {
        if (half == 0) { vA.x += ox; vA.y += oy; } else cA = -1;
    }
    // pair merge within B (p2 <- p3)
    oc = __shfl_xor(cB, 32);
    ox = __shfl_xor(vB.x, 32); oy = __shfl_xor(vB.y, 32);
    if (cB >= 0 && cB == oc) {
        if (half == 0) { vB.x += ox; vB.y += oy; } else cB = -1;
    }
    // cross merge (A <- B), per-lane registers
    if (cB >= 0 && cB == cA) { vA.x += vB.x; vA.y += vB.y; cB = -1; }

    __half2* rep = stage + (size_t)(q & (KREP-1)) * ((size_t)NCELL*32);
    if (cA >= 0) {
        __half2 h; h.x = __float2half(vA.x); h.y = __float2half(vA.y);
        pk_add_f16(&rep[(size_t)cA*32 + k], h);
    }
    if (cB >= 0) {
        __half2 h; h.x = __float2half(vB.x); h.y = __float2half(vB.y);
        pk_add_f16(&rep[(size_t)cB*32 + k], h);
    }
}

// Sum 4 fp16 replicas (B, X*Y, C) -> (B, C, X*Y) f32 output.
__global__ __launch_bounds__(512)
void trans_h2(const __half2* __restrict__ stage, float* __restrict__ out) {
    __shared__ float tile[64][65];
    int b   = blockIdx.y;
    int xy0 = blockIdx.x * 64;
    int tx  = threadIdx.x & 31;    // half2 index (channel pair)
    int ty  = threadIdx.x >> 5;    // 0..15

    const size_t rstride = (size_t)NCELL*32;
    #pragma unroll
    for (int i = 0; i < 4; ++i) {
        int r = ty + i*16;         // 0..63
        size_t idx = ((size_t)b*(X_*Y_) + xy0 + r)*32 + tx;
        float sx = 0.f, sy = 0.f;
        #pragma unroll
        for (int kk = 0; kk < KREP; ++kk) {
            float2 f = __half22float2(stage[kk*rstride + idx]);
            sx += f.x; sy += f.y;
        }
        tile[r][2*tx]   = sx;
        tile[r][2*tx+1] = sy;
    }
    __syncthreads();
    int cw = threadIdx.x >> 6;     // 0..7
    int j  = threadIdx.x & 63;
    #pragma unroll
    for (int k = 0; k < 8; ++k) {
        int c = cw*8 + k;
        out[((size_t)(b*C_ + c))*(X_*Y_) + xy0 + j] = tile[j][c];
    }
}

// Fallback (tiny ws): direct f32 atomics into (B,C,X,Y) output.
__global__ __launch_bounds__(256)
void scatter_fallback(const float* __restrict__ feat,
                      const int* __restrict__ rank,
                      float* __restrict__ dst) {
    int tid  = blockIdx.x * blockDim.x + threadIdx.x;
    int p    = tid >> 6;
    int lane = tid & 63;
    if (p >= NPTS) return;
    int cell = rank[p];
    if (cell < 0) return;
    int b = cell / (X_*Y_);
    int xy = cell % (X_*Y_);
    float v = feat[(size_t)p*C_ + lane];
    unsafeAtomicAdd(&dst[((size_t)(b*C_ + lane))*(X_*Y_) + xy], v);
}

extern "C" void kernel_launch(void* const* d_in, const int* in_sizes, int n_in,
                              void* d_out, int out_size, void* d_ws, size_t ws_size,
                              hipStream_t stream) {
    const float* feat       = (const float*)d_in[0];
    const float* post_trans = (const float*)d_in[1];
    const float* post_rots  = (const float*)d_in[2];
    const float* intr       = (const float*)d_in[3];
    const float* extr       = (const float*)d_in[4];
    const float* frustum    = (const float*)d_in[5];
    const float* bev_res    = (const float*)d_in[6];
    const float* bev_start  = (const float*)d_in[7];
    float* out = (float*)d_out;

    // ws layout
    char* base = (char*)d_ws;
    double* mats   = (double*)base;                    size_t off = 4096;
    int* rank      = (int*)(base + off);               off += (size_t)NPTS*4;
    off = (off + 511) & ~(size_t)511;
    __half2* stage = (__half2*)(base + off);
    const size_t stage_bytes = (size_t)KREP * NCELL * C_ * 2;  // 40.96 MB
    off += stage_bytes;
    bool have_ws = (ws_size >= off);

    hipLaunchKernelGGL(prep_kernel, dim3(1), dim3(16), 0, stream,
                       post_rots, intr, extr, mats);

    const int pt_blocks = (NPTS + 255) / 256;

    geom_kernel<<<pt_blocks, 256, 0, stream>>>(post_trans, frustum, bev_res,
                                               bev_start, mats, rank);

    if (have_ws) {
        hipMemsetAsync(stage, 0, stage_bytes, stream);
        const int sc_blocks = (int)(((size_t)(NPTS/4)*64 + 255) / 256);  // 21648
        scatter_h4<<<sc_blocks, 256, 0, stream>>>((const float2*)feat, rank, stage);
        trans_h2<<<dim3((X_*Y_)/64, B_), 512, 0, stream>>>(stage, out);
    } else {
        hipMemsetAsync(out, 0, (size_t)out_size*sizeof(float), stream);
        const int wv_blocks = (int)(((size_t)NPTS*64 + 255) / 256);
        scatter_fallback<<<wv_blocks, 256, 0, stream>>>(feat, rank, out);
    }
}